// Round 1
// baseline (211.516 us; speedup 1.0000x reference)
//
#include <hip/hip_runtime.h>

// Problem constants (from the reference)
#define S_      7
#define SS_     49
#define B_      2
#define C_      20
#define F_      30                 // B*5 + C
#define N_IMG_  16384
#define NCELL_  (N_IMG_ * SS_)     // 802816
#define COORD_  5.0f
#define NOOBJ_  0.5f

#define TPB           256
#define CELLS_PER_BLK TPB
#define NBLK          (NCELL_ / CELLS_PER_BLK)      // 3136 exactly
#define FLT_PER_BLK   (CELLS_PER_BLK * F_)          // 7680
#define VEC4_PER_BLK  (FLT_PER_BLK / 4)             // 1920

__device__ __forceinline__ float iou_f(const float* pb, const float* tb) {
    // mirror the reference op-for-op (x/2 == x*0.5f exactly)
    float xA = fmaxf(pb[0] - pb[2] * 0.5f, tb[0] - tb[2] * 0.5f);
    float yA = fmaxf(pb[1] - pb[3] * 0.5f, tb[1] - tb[3] * 0.5f);
    float xB = fminf(pb[0] + pb[2] * 0.5f, tb[0] + tb[2] * 0.5f);
    float yB = fminf(pb[1] + pb[3] * 0.5f, tb[1] + tb[3] * 0.5f);
    float inter = fmaxf(0.f, xB - xA) * fmaxf(0.f, yB - yA);
    float areaA = pb[2] * pb[3];
    float areaB = tb[2] * tb[3];
    return inter / (areaA + areaB - inter);
}

__global__ __launch_bounds__(TPB) void mploss_kernel(
        const float* __restrict__ preds,
        const float* __restrict__ targets,
        float* __restrict__ out) {
    __shared__ float s_p[FLT_PER_BLK];
    __shared__ float s_t[FLT_PER_BLK];
    __shared__ float s_red[TPB / 64];

    const int tid = threadIdx.x;
    const long base4 = (long)blockIdx.x * VEC4_PER_BLK;
    const float4* p4 = (const float4*)preds;
    const float4* t4 = (const float4*)targets;
    float4* sp4 = (float4*)s_p;
    float4* st4 = (float4*)s_t;

    // Coalesced staging: contiguous float4 loads, 16 B/lane.
    #pragma unroll
    for (int i = tid; i < VEC4_PER_BLK; i += TPB) {
        sp4[i] = p4[base4 + i];
        st4[i] = t4[base4 + i];
    }
    __syncthreads();

    const float* p = s_p + tid * F_;   // this thread's cell: probs[0..19], conf[20..21], box[22..29]
    const float* q = s_t + tid * F_;

    float l = 0.f;

    // NOOBJ * sum((p_conf - t_conf)^2) over both boxes, all cells
    {
        float d0 = p[20] - q[20];
        float d1 = p[21] - q[21];
        l += NOOBJ_ * (d0 * d0 + d1 * d1);
    }

    const bool obj = q[20] > 0.f;
    if (obj) {
        // class-prob term
        float sprob = 0.f;
        #pragma unroll
        for (int f = 0; f < C_; ++f) {
            float d = p[f] - q[f];
            sprob += d * d;
        }
        l += sprob;

        // responsible box via IoU argmax (numpy argmax: first max wins -> strict >)
        float i0 = iou_f(p + 22, q + 22);
        float i1 = iou_f(p + 26, q + 26);
        int best = (i1 > i0) ? 1 : 0;

        // confidence term for responsible box
        float dc = p[20 + best] - q[20 + best];
        l += (1.0f - NOOBJ_) * dc * dc;

        // coord term (obj=true so tb_wh == tb[2:4])
        const float* pb = p + 22 + 4 * best;
        const float* tb = q + 22 + 4 * best;
        float bx = pb[0] - tb[0];
        float by = pb[1] - tb[1];
        float bw = sqrtf(pb[2]) - sqrtf(tb[2]);
        float bh = sqrtf(pb[3]) - sqrtf(tb[3]);
        l += COORD_ * (bx * bx + by * by + bw * bw + bh * bh);
    }

    // wave (64-lane) shuffle reduction
    #pragma unroll
    for (int off = 32; off > 0; off >>= 1)
        l += __shfl_down(l, off, 64);

    const int wave = tid >> 6;
    const int lane = tid & 63;
    if (lane == 0) s_red[wave] = l;
    __syncthreads();
    if (tid == 0) {
        float tot = s_red[0] + s_red[1] + s_red[2] + s_red[3];
        atomicAdd(out, tot * (1.0f / (float)N_IMG_));
    }
}

extern "C" void kernel_launch(void* const* d_in, const int* in_sizes, int n_in,
                              void* d_out, int out_size, void* d_ws, size_t ws_size,
                              hipStream_t stream) {
    const float* preds   = (const float*)d_in[0];
    const float* targets = (const float*)d_in[1];
    float* out = (float*)d_out;

    // d_out is poisoned 0xAA before every launch; zero it (graph-capture safe)
    hipMemsetAsync(out, 0, sizeof(float) * (size_t)out_size, stream);

    mploss_kernel<<<NBLK, TPB, 0, stream>>>(preds, targets, out);
}

// Round 2
// 203.057 us; speedup vs baseline: 1.0417x; 1.0417x over previous
//
#include <hip/hip_runtime.h>

// Problem constants (from the reference)
#define S_      7
#define SS_     49
#define B_      2
#define C_      20
#define F_      30                 // B*5 + C
#define N_IMG_  16384
#define NCELL_  (N_IMG_ * SS_)     // 802816
#define COORD_  5.0f
#define NOOBJ_  0.5f

#define TPB           256
#define CELLS_PER_BLK TPB
#define NBLK          (NCELL_ / CELLS_PER_BLK)      // 3136 exactly
#define FLT_PER_BLK   (CELLS_PER_BLK * F_)          // 7680 floats = 30 KB
#define VEC4_PER_BLK  (FLT_PER_BLK / 4)             // 1920 float4 = 30 chunks of 64

typedef const __attribute__((address_space(1))) void g_void;
typedef __attribute__((address_space(3))) void lds_void;

__device__ __forceinline__ float iou_f(const float* pb, const float* tb) {
    float xA = fmaxf(pb[0] - pb[2] * 0.5f, tb[0] - tb[2] * 0.5f);
    float yA = fmaxf(pb[1] - pb[3] * 0.5f, tb[1] - tb[3] * 0.5f);
    float xB = fminf(pb[0] + pb[2] * 0.5f, tb[0] + tb[2] * 0.5f);
    float yB = fminf(pb[1] + pb[3] * 0.5f, tb[1] + tb[3] * 0.5f);
    float inter = fmaxf(0.f, xB - xA) * fmaxf(0.f, yB - yA);
    float areaA = pb[2] * pb[3];
    float areaB = tb[2] * tb[3];
    return inter / (areaA + areaB - inter);
}

__global__ __launch_bounds__(TPB) void mploss_kernel(
        const float* __restrict__ preds,
        const float* __restrict__ targets,
        float* __restrict__ out) {
    __shared__ alignas(16) float s_p[FLT_PER_BLK];
    __shared__ alignas(16) float s_t[FLT_PER_BLK];
    __shared__ float s_red[TPB / 64];

    const int tid  = threadIdx.x;
    const int lane = tid & 63;
    const int wave = tid >> 6;

    const float4* p4 = (const float4*)preds   + (long)blockIdx.x * VEC4_PER_BLK;
    const float4* t4 = (const float4*)targets + (long)blockIdx.x * VEC4_PER_BLK;

    // Async global->LDS staging: 30 chunks of (64 lanes x 16 B) per array.
    // Wave w takes chunks w, w+4, ... -> 7-8 chunks x 2 arrays = ~15 async
    // 1KB DMAs in flight per wave, no VGPR round-trip, no per-iter waitcnt.
    for (int c = wave; c < 30; c += 4) {
        __builtin_amdgcn_global_load_lds(
            (g_void*)(p4 + c * 64 + lane),
            (lds_void*)(s_p + c * 256), 16, 0, 0);
        __builtin_amdgcn_global_load_lds(
            (g_void*)(t4 + c * 64 + lane),
            (lds_void*)(s_t + c * 256), 16, 0, 0);
    }
    __syncthreads();   // compiler emits s_waitcnt vmcnt(0) before s_barrier

    const float* p = s_p + tid * F_;   // probs[0..19], conf[20..21], box[22..29]
    const float* q = s_t + tid * F_;

    float l = 0.f;

    // NOOBJ * sum((p_conf - t_conf)^2) over both boxes, all cells
    {
        float d0 = p[20] - q[20];
        float d1 = p[21] - q[21];
        l += NOOBJ_ * (d0 * d0 + d1 * d1);
    }

    const bool obj = q[20] > 0.f;
    if (obj) {
        // class-prob term
        float sprob = 0.f;
        #pragma unroll
        for (int f = 0; f < C_; ++f) {
            float d = p[f] - q[f];
            sprob += d * d;
        }
        l += sprob;

        // responsible box via IoU argmax (numpy argmax: first max wins -> strict >)
        float i0 = iou_f(p + 22, q + 22);
        float i1 = iou_f(p + 26, q + 26);
        int best = (i1 > i0) ? 1 : 0;

        // confidence term for responsible box
        float dc = p[20 + best] - q[20 + best];
        l += (1.0f - NOOBJ_) * dc * dc;

        // coord term (obj=true so tb_wh == tb[2:4])
        const float* pb = p + 22 + 4 * best;
        const float* tb = q + 22 + 4 * best;
        float bx = pb[0] - tb[0];
        float by = pb[1] - tb[1];
        float bw = sqrtf(pb[2]) - sqrtf(tb[2]);
        float bh = sqrtf(pb[3]) - sqrtf(tb[3]);
        l += COORD_ * (bx * bx + by * by + bw * bw + bh * bh);
    }

    // wave (64-lane) shuffle reduction
    #pragma unroll
    for (int off = 32; off > 0; off >>= 1)
        l += __shfl_down(l, off, 64);

    if (lane == 0) s_red[wave] = l;
    __syncthreads();
    if (tid == 0) {
        float tot = s_red[0] + s_red[1] + s_red[2] + s_red[3];
        atomicAdd(out, tot * (1.0f / (float)N_IMG_));
    }
}

extern "C" void kernel_launch(void* const* d_in, const int* in_sizes, int n_in,
                              void* d_out, int out_size, void* d_ws, size_t ws_size,
                              hipStream_t stream) {
    const float* preds   = (const float*)d_in[0];
    const float* targets = (const float*)d_in[1];
    float* out = (float*)d_out;

    // d_out is poisoned 0xAA before every launch; zero it (graph-capture safe)
    hipMemsetAsync(out, 0, sizeof(float) * (size_t)out_size, stream);

    mploss_kernel<<<NBLK, TPB, 0, stream>>>(preds, targets, out);
}